// Round 1
// baseline (1027.196 us; speedup 1.0000x reference)
//
#include <hip/hip_runtime.h>

#define T_SEQ 20
#define S_SEQ 8192
#define D_IN  100
#define H_DIM 81
#define NSTEP (T_SEQ * S_SEQ)     // 163840
#define WROW  (D_IN + H_DIM)      // 181
#define CHUNK_L 128
#define WARM    256
#define NCHUNK  (NSTEP / CHUNK_L) // 1280
#define UVEC_N  (T_SEQ * H_DIM)   // 1620

__device__ __forceinline__ float fast_tanh(float v) {
    float e = __expf(2.0f * v);
    return 1.0f - 2.0f * __builtin_amdgcn_rcpf(e + 1.0f);
}

// ---------------- x_proj: xp[i][j] = b1[j] + sum_d x[i][d] * W1[j][d] ----------------
__global__ __launch_bounds__(256) void xproj_kernel(
    const float* __restrict__ x, const float* __restrict__ W1,
    const float* __restrict__ b1, float* __restrict__ xp)
{
    int idx = blockIdx.x * 256 + threadIdx.x;
    if (idx >= NSTEP * H_DIM) return;
    int i = idx / H_DIM;
    int j = idx - i * H_DIM;
    const float* xr = x + i * D_IN;
    const float* wr = W1 + j * WROW;
    float a0 = b1[j], a1 = 0.f, a2 = 0.f, a3 = 0.f;
    #pragma unroll
    for (int d = 0; d < D_IN; d += 4) {
        a0 += xr[d + 0] * wr[d + 0];
        a1 += xr[d + 1] * wr[d + 1];
        a2 += xr[d + 2] * wr[d + 2];
        a3 += xr[d + 3] * wr[d + 3];
    }
    xp[idx] = (a0 + a1) + (a2 + a3);
}

// ---------------- recurrence: chunked with warmup (echo-state forgetting) ----------------
// One wave (64 threads) per chunk. Lane l owns rows j0=l and (if l<17) j1=l+64.
// h broadcast via LDS; Wh rows in registers; xp prefetched 4 steps ahead.
template <bool FUSED>
__global__ __launch_bounds__(64, 1) void rnn_kernel(
    const float* __restrict__ xp, const float* __restrict__ x,
    const float* __restrict__ W1, const float* __restrict__ b1,
    const float* __restrict__ hidden, float* __restrict__ uvec)
{
    __shared__ float h_lds[H_DIM];
    __shared__ float xbuf[2][D_IN];   // only used when FUSED

    const int lane = threadIdx.x;
    const int c = blockIdx.x;
    const int own_start = c * CHUNK_L;
    const int own_end   = own_start + CHUNK_L;
    const int s0        = (own_start > WARM) ? (own_start - WARM) : 0;
    const int nsteps    = own_end - s0;            // 128/256/384, all %4==0

    const int j0 = lane;                            // 0..63 (<81 always)
    const bool has1 = (lane < (H_DIM - 64));        // lanes 0..16
    const int jj1 = has1 ? (lane + 64) : lane;      // clamp to stay in-bounds

    // Wh rows into registers (162 VGPRs)
    float wh0[H_DIM], wh1[H_DIM];
    {
        const float* w0 = W1 + j0  * WROW + D_IN;
        const float* w1 = W1 + jj1 * WROW + D_IN;
        #pragma unroll
        for (int k = 0; k < H_DIM; ++k) { wh0[k] = w0[k]; wh1[k] = w1[k]; }
    }

    float wx0[FUSED ? D_IN : 1], wx1[FUSED ? D_IN : 1];
    float bb0 = 0.f, bb1 = 0.f;
    if constexpr (FUSED) {
        const float* v0 = W1 + j0  * WROW;
        const float* v1 = W1 + jj1 * WROW;
        #pragma unroll
        for (int d = 0; d < D_IN; ++d) { wx0[d] = v0[d]; wx1[d] = v1[d]; }
        bb0 = b1[j0]; bb1 = b1[jj1];
    }

    // init hidden: true init for chunk 0, zeros for warmup chunks (forgotten anyway)
    h_lds[j0] = (c == 0) ? hidden[j0] : 0.0f;
    if (has1) h_lds[lane + 64] = (c == 0) ? hidden[lane + 64] : 0.0f;

    // prefetch queue (non-fused) / first x row stage (fused)
    float xq0[4], xq1[4];
    if constexpr (!FUSED) {
        #pragma unroll
        for (int p = 0; p < 4; ++p) {
            int st = s0 + p;
            xq0[p] = xp[st * H_DIM + j0];
            xq1[p] = xp[st * H_DIM + jj1];
        }
    } else {
        xbuf[0][lane] = x[s0 * D_IN + lane];
        if (lane < D_IN - 64) xbuf[0][lane + 64] = x[s0 * D_IN + 64 + lane];
    }
    __syncthreads();

    for (int ii = 0; ii < nsteps; ii += 4) {
        const int base = s0 + ii;
        #pragma unroll
        for (int p = 0; p < 4; ++p) {
            const int st = base + p;
            float xv0, xv1;
            if constexpr (!FUSED) {
                xv0 = xq0[p]; xv1 = xq1[p];
                int ld = st + 4; if (ld > own_end - 1) ld = own_end - 1;
                xq0[p] = xp[ld * H_DIM + j0];
                xq1[p] = xp[ld * H_DIM + jj1];
            } else {
                // stage next x row into the other buffer
                int nx = st + 1; if (nx > own_end - 1) nx = own_end - 1;
                const int ns = (p + 1) & 1;
                xbuf[ns][lane] = x[nx * D_IN + lane];
                if (lane < D_IN - 64) xbuf[ns][lane + 64] = x[nx * D_IN + 64 + lane];
                // x_proj on the fly (independent of h -> overlaps the LDS wait)
                float p0 = bb0, p1 = 0.f, q0 = bb1, q1 = 0.f;
                #pragma unroll
                for (int d = 0; d < D_IN; d += 2) {
                    float xa = xbuf[p & 1][d], xb = xbuf[p & 1][d + 1];
                    p0 += wx0[d]     * xa; p1 += wx0[d + 1] * xb;
                    q0 += wx1[d]     * xa; q1 += wx1[d + 1] * xb;
                }
                xv0 = p0 + p1; xv1 = q0 + q1;
            }

            // h part: 4 independent FMA chains per output row
            float a0 = 0.f, a1 = 0.f, a2 = 0.f, a3 = 0.f;
            float c0 = 0.f, c1 = 0.f, c2 = 0.f, c3 = 0.f;
            #pragma unroll
            for (int k = 0; k < 80; k += 4) {
                float h0 = h_lds[k], h1 = h_lds[k + 1], h2 = h_lds[k + 2], h3 = h_lds[k + 3];
                a0 += wh0[k] * h0; a1 += wh0[k + 1] * h1; a2 += wh0[k + 2] * h2; a3 += wh0[k + 3] * h3;
                c0 += wh1[k] * h0; c1 += wh1[k + 1] * h1; c2 += wh1[k + 2] * h2; c3 += wh1[k + 3] * h3;
            }
            {
                float h80 = h_lds[80];
                a0 += wh0[80] * h80; c0 += wh1[80] * h80;
            }
            float z0 = ((a0 + a1) + (a2 + a3)) + xv0;
            float z1 = ((c0 + c1) + (c2 + c3)) + xv1;
            float hn0 = fast_tanh(z0);
            float hn1 = fast_tanh(z1);

            __syncthreads();               // single wave -> waitcnt, not s_barrier
            h_lds[j0] = hn0;
            if (has1) h_lds[lane + 64] = hn1;
            __syncthreads();

            if (st >= own_start && ((st + 1) & (S_SEQ - 1)) == 0) {
                int t = ((st + 1) >> 13) - 1;
                uvec[t * H_DIM + j0] = hn0;
                if (has1) uvec[t * H_DIM + lane + 64] = hn1;
            }
        }
    }
}

// ---------------- head: out[o] = sigmoid(b2[o] + sum_n W2[o][n]*uvec[n]) ----------------
__global__ __launch_bounds__(64) void out_kernel(
    const float* __restrict__ uvec, const float* __restrict__ W2,
    const float* __restrict__ b2, float* __restrict__ out)
{
    int lane = threadIdx.x;
    float s0 = 0.f, s1 = 0.f;
    for (int n = lane; n < UVEC_N; n += 64) {
        float u = uvec[n];
        s0 += u * W2[n];
        s1 += u * W2[UVEC_N + n];
    }
    #pragma unroll
    for (int off = 32; off; off >>= 1) {
        s0 += __shfl_down(s0, off);
        s1 += __shfl_down(s1, off);
    }
    if (lane == 0) {
        out[0] = 1.0f / (1.0f + __expf(-(s0 + b2[0])));
        out[1] = 1.0f / (1.0f + __expf(-(s1 + b2[1])));
    }
}

extern "C" void kernel_launch(void* const* d_in, const int* in_sizes, int n_in,
                              void* d_out, int out_size, void* d_ws, size_t ws_size,
                              hipStream_t stream) {
    const float* x      = (const float*)d_in[0];
    const float* hidden = (const float*)d_in[1];
    const float* W1     = (const float*)d_in[2];
    const float* b1     = (const float*)d_in[3];
    const float* W2     = (const float*)d_in[4];
    const float* b2     = (const float*)d_in[5];
    float* out = (float*)d_out;

    const size_t xp_bytes   = (size_t)NSTEP * H_DIM * sizeof(float); // ~53 MB
    const size_t uvec_bytes = (size_t)UVEC_N * sizeof(float);

    if (ws_size >= xp_bytes + uvec_bytes) {
        float* xp   = (float*)d_ws;
        float* uvec = (float*)((char*)d_ws + xp_bytes);
        int total = NSTEP * H_DIM;
        xproj_kernel<<<(total + 255) / 256, 256, 0, stream>>>(x, W1, b1, xp);
        rnn_kernel<false><<<NCHUNK, 64, 0, stream>>>(xp, x, W1, b1, hidden, uvec);
        out_kernel<<<1, 64, 0, stream>>>(uvec, W2, b2, out);
    } else {
        // fallback: compute x_proj on the fly inside the recurrence
        float* uvec = (float*)d_ws;
        rnn_kernel<true><<<NCHUNK, 64, 0, stream>>>(nullptr, x, W1, b1, hidden, uvec);
        out_kernel<<<1, 64, 0, stream>>>(uvec, W2, b2, out);
    }
}

// Round 2
// 300.854 us; speedup vs baseline: 3.4143x; 3.4143x over previous
//
#include <hip/hip_runtime.h>

#define T_SEQ 20
#define S_SEQ 8192
#define D_IN  100
#define H_DIM 81
#define NSTEP (T_SEQ * S_SEQ)     // 163840
#define WROW  (D_IN + H_DIM)      // 181
#define CHUNK_L 128
#define WARM    96
#define NCHUNK  (NSTEP / CHUNK_L) // 1280
#define UVEC_N  (T_SEQ * H_DIM)   // 1620

__device__ __forceinline__ float fast_tanh(float v) {
    float e = __expf(2.0f * v);
    return 1.0f - 2.0f * __builtin_amdgcn_rcpf(e + 1.0f);
}

// broadcast lane k's value of v to all lanes (SGPR result); k must be constant
__device__ __forceinline__ float rl(float v, int k) {
    return __uint_as_float(__builtin_amdgcn_readlane(__float_as_uint(v), k));
}

// ---------------- x_proj: xp[i][j] = b1[j] + sum_d x[i][d] * Wx[j][d] ----------------
// 4 waves/block; each wave owns 64 consecutive steps. Lane owns output rows
// j0=lane, j1=lane+64 (lanes<17). Wx rows in VGPRs; x row distributed across
// lanes (coalesced 4B loads) and broadcast via v_readlane. No LDS.
__global__ __launch_bounds__(256) void xproj_kernel(
    const float* __restrict__ x, const float* __restrict__ W1,
    const float* __restrict__ b1, float* __restrict__ xp)
{
    const int lane = threadIdx.x & 63;
    const int gwave = blockIdx.x * 4 + (threadIdx.x >> 6);
    const int base = gwave * 64;                 // 64 steps per wave

    const int j0 = lane;
    const bool has1 = (lane < (H_DIM - 64));     // lanes 0..16
    const int jj1 = has1 ? (lane + 64) : lane;

    float wx0[D_IN], wx1[D_IN];
    {
        const float* v0 = W1 + j0  * WROW;
        const float* v1 = W1 + jj1 * WROW;
        #pragma unroll
        for (int d = 0; d < D_IN; ++d) { wx0[d] = v0[d]; wx1[d] = v1[d]; }
    }
    const float bb0 = b1[j0];
    const float bb1 = b1[jj1];

    // x-row prefetch queue, 4 deep: lane k holds x[st][k] (va) and x[st][64+k] (vb, k<36)
    float qa[4], qb[4];
    #pragma unroll
    for (int p = 0; p < 4; ++p) {
        int st = base + p;
        qa[p] = x[(size_t)st * D_IN + lane];
        qb[p] = (lane < (D_IN - 64)) ? x[(size_t)st * D_IN + 64 + lane] : 0.0f;
    }

    for (int ii = 0; ii < 64; ii += 4) {
        #pragma unroll
        for (int p = 0; p < 4; ++p) {
            const int st = base + ii + p;
            const float va = qa[p], vb = qb[p];
            int ld = st + 4; if (ld > NSTEP - 1) ld = NSTEP - 1;
            qa[p] = x[(size_t)ld * D_IN + lane];
            qb[p] = (lane < (D_IN - 64)) ? x[(size_t)ld * D_IN + 64 + lane] : 0.0f;

            float a0 = bb0, a1 = 0.f, a2 = 0.f, a3 = 0.f;
            float c0 = bb1, c1 = 0.f, c2 = 0.f, c3 = 0.f;
            #pragma unroll
            for (int k = 0; k < 64; k += 4) {
                float x0 = rl(va, k), x1 = rl(va, k + 1), x2 = rl(va, k + 2), x3 = rl(va, k + 3);
                a0 = fmaf(x0, wx0[k],     a0); c0 = fmaf(x0, wx1[k],     c0);
                a1 = fmaf(x1, wx0[k + 1], a1); c1 = fmaf(x1, wx1[k + 1], c1);
                a2 = fmaf(x2, wx0[k + 2], a2); c2 = fmaf(x2, wx1[k + 2], c2);
                a3 = fmaf(x3, wx0[k + 3], a3); c3 = fmaf(x3, wx1[k + 3], c3);
            }
            #pragma unroll
            for (int k = 64; k < 100; k += 4) {
                float x0 = rl(vb, k - 64), x1 = rl(vb, k - 63), x2 = rl(vb, k - 62), x3 = rl(vb, k - 61);
                a0 = fmaf(x0, wx0[k],     a0); c0 = fmaf(x0, wx1[k],     c0);
                a1 = fmaf(x1, wx0[k + 1], a1); c1 = fmaf(x1, wx1[k + 1], c1);
                a2 = fmaf(x2, wx0[k + 2], a2); c2 = fmaf(x2, wx1[k + 2], c2);
                a3 = fmaf(x3, wx0[k + 3], a3); c3 = fmaf(x3, wx1[k + 3], c3);
            }
            float r0 = (a0 + a1) + (a2 + a3);
            float r1 = (c0 + c1) + (c2 + c3);
            xp[(size_t)st * H_DIM + j0] = r0;
            if (has1) xp[(size_t)st * H_DIM + jj1] = r1;
        }
    }
}

// ---------------- recurrence: chunked warmup, h in registers, readlane broadcast ----------------
// One wave per chunk. No LDS, no barriers. Lane owns rows j0=lane, j1=lane+64 (lanes<17).
__global__ __launch_bounds__(64, 1) void rnn_kernel(
    const float* __restrict__ xp, const float* __restrict__ W1,
    const float* __restrict__ hidden, float* __restrict__ uvec)
{
    const int lane = threadIdx.x;
    const int c = blockIdx.x;
    const int own_start = c * CHUNK_L;
    const int own_end   = own_start + CHUNK_L;
    const int s0        = (own_start > WARM) ? (own_start - WARM) : 0;
    const int nsteps    = own_end - s0;          // 128 (c==0) or 224, both %4==0

    const int j0 = lane;
    const bool has1 = (lane < (H_DIM - 64));
    const int jj1 = has1 ? (lane + 64) : lane;

    // Wh rows into registers (162 VGPRs)
    float wh0[H_DIM], wh1[H_DIM];
    {
        const float* w0 = W1 + j0  * WROW + D_IN;
        const float* w1 = W1 + jj1 * WROW + D_IN;
        #pragma unroll
        for (int k = 0; k < H_DIM; ++k) { wh0[k] = w0[k]; wh1[k] = w1[k]; }
    }

    // hidden state in registers: h0 = h[lane], h1 = h[lane+64] (lanes<17)
    float h0 = (c == 0) ? hidden[j0]  : 0.0f;
    float h1 = (c == 0) ? hidden[jj1] : 0.0f;

    // xp prefetch queue, 4 deep
    float xq0[4], xq1[4];
    #pragma unroll
    for (int p = 0; p < 4; ++p) {
        int st = s0 + p;
        xq0[p] = xp[(size_t)st * H_DIM + j0];
        xq1[p] = xp[(size_t)st * H_DIM + jj1];
    }

    for (int ii = 0; ii < nsteps; ii += 4) {
        const int base = s0 + ii;
        #pragma unroll
        for (int p = 0; p < 4; ++p) {
            const int st = base + p;
            const float xv0 = xq0[p], xv1 = xq1[p];
            int ld = st + 4; if (ld > own_end - 1) ld = own_end - 1;
            xq0[p] = xp[(size_t)ld * H_DIM + j0];
            xq1[p] = xp[(size_t)ld * H_DIM + jj1];

            float a0 = xv0, a1 = 0.f, a2 = 0.f, a3 = 0.f;
            float c0 = xv1, c1 = 0.f, c2 = 0.f, c3 = 0.f;
            #pragma unroll
            for (int k = 0; k < 64; k += 4) {
                float h0k = rl(h0, k), h1k = rl(h0, k + 1), h2k = rl(h0, k + 2), h3k = rl(h0, k + 3);
                a0 = fmaf(h0k, wh0[k],     a0); c0 = fmaf(h0k, wh1[k],     c0);
                a1 = fmaf(h1k, wh0[k + 1], a1); c1 = fmaf(h1k, wh1[k + 1], c1);
                a2 = fmaf(h2k, wh0[k + 2], a2); c2 = fmaf(h2k, wh1[k + 2], c2);
                a3 = fmaf(h3k, wh0[k + 3], a3); c3 = fmaf(h3k, wh1[k + 3], c3);
            }
            #pragma unroll
            for (int k = 64; k < 80; k += 4) {
                float h0k = rl(h1, k - 64), h1k = rl(h1, k - 63), h2k = rl(h1, k - 62), h3k = rl(h1, k - 61);
                a0 = fmaf(h0k, wh0[k],     a0); c0 = fmaf(h0k, wh1[k],     c0);
                a1 = fmaf(h1k, wh0[k + 1], a1); c1 = fmaf(h1k, wh1[k + 1], c1);
                a2 = fmaf(h2k, wh0[k + 2], a2); c2 = fmaf(h2k, wh1[k + 2], c2);
                a3 = fmaf(h3k, wh0[k + 3], a3); c3 = fmaf(h3k, wh1[k + 3], c3);
            }
            {
                float hk = rl(h1, 16);
                a0 = fmaf(hk, wh0[80], a0); c0 = fmaf(hk, wh1[80], c0);
            }
            const float z0 = (a0 + a1) + (a2 + a3);
            const float z1 = (c0 + c1) + (c2 + c3);
            h0 = fast_tanh(z0);
            h1 = fast_tanh(z1);

            if (((st + 1) & (S_SEQ - 1)) == 0 && st >= own_start) {
                int t = ((st + 1) >> 13) - 1;
                uvec[t * H_DIM + j0] = h0;
                if (has1) uvec[t * H_DIM + jj1] = h1;
            }
        }
    }
}

// ---------------- head ----------------
__global__ __launch_bounds__(64) void out_kernel(
    const float* __restrict__ uvec, const float* __restrict__ W2,
    const float* __restrict__ b2, float* __restrict__ out)
{
    int lane = threadIdx.x;
    float s0 = 0.f, s1 = 0.f;
    for (int n = lane; n < UVEC_N; n += 64) {
        float u = uvec[n];
        s0 += u * W2[n];
        s1 += u * W2[UVEC_N + n];
    }
    #pragma unroll
    for (int off = 32; off; off >>= 1) {
        s0 += __shfl_down(s0, off);
        s1 += __shfl_down(s1, off);
    }
    if (lane == 0) {
        out[0] = 1.0f / (1.0f + __expf(-(s0 + b2[0])));
        out[1] = 1.0f / (1.0f + __expf(-(s1 + b2[1])));
    }
}

extern "C" void kernel_launch(void* const* d_in, const int* in_sizes, int n_in,
                              void* d_out, int out_size, void* d_ws, size_t ws_size,
                              hipStream_t stream) {
    const float* x      = (const float*)d_in[0];
    const float* hidden = (const float*)d_in[1];
    const float* W1     = (const float*)d_in[2];
    const float* b1     = (const float*)d_in[3];
    const float* W2     = (const float*)d_in[4];
    const float* b2     = (const float*)d_in[5];
    float* out = (float*)d_out;

    const size_t xp_bytes = (size_t)NSTEP * H_DIM * sizeof(float); // ~53 MB
    float* xp   = (float*)d_ws;
    float* uvec = (float*)((char*)d_ws + xp_bytes);

    // 640 blocks x 4 waves, each wave owns 64 steps
    xproj_kernel<<<NSTEP / 256, 256, 0, stream>>>(x, W1, b1, xp);
    rnn_kernel<<<NCHUNK, 64, 0, stream>>>(xp, W1, hidden, uvec);
    out_kernel<<<1, 64, 0, stream>>>(uvec, W2, b2, out);
}